// Round 4
// baseline (394.855 us; speedup 1.0000x reference)
//
#include <hip/hip_runtime.h>
#include <cstdint>
#include <math.h>

// Problem constants
constexpr int NH  = 16;    // heads
constexpr int DKH = 64;    // head dim
constexpr int SEQ = 1024;  // LT == LS
constexpr int NB  = 4;     // batch
constexpr int DM  = 1024;  // d_model
constexpr int DF  = 4096;  // ffn dim

typedef __bf16 bf16;
typedef __bf16 bf16x4 __attribute__((ext_vector_type(4)));
typedef __bf16 bf16x8 __attribute__((ext_vector_type(8)));
typedef float  f32x4  __attribute__((ext_vector_type(4)));

#define MFMA16(a, b, c) __builtin_amdgcn_mfma_f32_16x16x32_bf16((a), (b), (c), 0, 0, 0)

__device__ __forceinline__ void gload_lds16(const void* g, void* l) {
  __builtin_amdgcn_global_load_lds(
      (const __attribute__((address_space(1))) unsigned int*)(uintptr_t)g,
      (__attribute__((address_space(3))) unsigned int*)(uintptr_t)l,
      16, 0, 0);
}

// LDS 16B-chunk swizzle for GEMM tiles (BK-wide rows)
template <int BK>
__device__ __forceinline__ int swz(int row) {
  return (BK == 32) ? ((row >> 1) & 3) : (row & 7);
}

// stage ROWS x BK bf16 tile (row-major, ldg stride) into LDS, 256 threads
template <int ROWS, int BK>
__device__ __forceinline__ void stage_tile(const bf16* __restrict__ g, int ldg,
                                           bf16* __restrict__ l, int t) {
  constexpr int ITER = ROWS * BK / 2048;
#pragma unroll
  for (int i = 0; i < ITER; ++i) {
    const int off = (i * 256 + t) * 8;
    const int row = off / BK;
    const int cc = (off & (BK - 1)) >> 3;
    const int sc = cc ^ swz<BK>(row);
    gload_lds16(&g[(size_t)row * ldg + (sc << 3)], &l[off]);
  }
}

// ---------------- fused prep: weight/activation casts + LN1, one dispatch ----------------
// bid 0..4095: w-mat casts (wq|wk|wv -> packed wqkv, wo)
// bid 4096..16383: big casts (w1, w2, enc)
// bid 16384..20479: LayerNorm(emb) rows -> qin_bf
__global__ __launch_bounds__(256) void prep_kernel(
    const float* __restrict__ wq, const float* __restrict__ wk,
    const float* __restrict__ wv, const float* __restrict__ wo,
    const float* __restrict__ w1, const float* __restrict__ w2,
    const float* __restrict__ enc, const float* __restrict__ emb,
    const float* __restrict__ g1, const float* __restrict__ be1,
    bf16* __restrict__ wqkv_bf, bf16* __restrict__ wo_bf,
    bf16* __restrict__ w1_bf, bf16* __restrict__ w2_bf,
    bf16* __restrict__ enc_bf, bf16* __restrict__ qin_bf) {
  const int bid = blockIdx.x, t = threadIdx.x;
  if (bid < 16384) {
    const float* in;
    bf16* out;
    int idx;
    if (bid < 4096) {
      const int sel = bid >> 10;
      in = sel == 0 ? wq : sel == 1 ? wk : sel == 2 ? wv : wo;
      out = sel == 3 ? wo_bf : wqkv_bf + ((size_t)sel << 20);
      idx = (bid & 1023) * 256 + t;
    } else {
      const int sel = (bid - 4096) >> 12;
      in = sel == 0 ? w1 : sel == 1 ? w2 : enc;
      out = sel == 0 ? w1_bf : sel == 1 ? w2_bf : enc_bf;
      idx = ((bid - 4096) & 4095) * 256 + t;
    }
    const float4 v = ((const float4*)in)[idx];
    bf16x4 ov;
    ov[0] = (bf16)v.x; ov[1] = (bf16)v.y; ov[2] = (bf16)v.z; ov[3] = (bf16)v.w;
    ((bf16x4*)out)[idx] = ov;
    return;
  }
  // LayerNorm(emb) row
  const int row = bid - 16384;
  const float4 v = ((const float4*)(emb + (size_t)row * DM))[t];
  float s  = v.x + v.y + v.z + v.w;
  float s2 = v.x * v.x + v.y * v.y + v.z * v.z + v.w * v.w;
#pragma unroll
  for (int m = 1; m < 64; m <<= 1) { s += __shfl_xor(s, m); s2 += __shfl_xor(s2, m); }
  __shared__ float red[8];
  const int w = t >> 6;
  if ((t & 63) == 0) { red[w] = s; red[4 + w] = s2; }
  __syncthreads();
  s  = red[0] + red[1] + red[2] + red[3];
  s2 = red[4] + red[5] + red[6] + red[7];
  const float mean = s * (1.f / DM);
  const float var  = s2 * (1.f / DM) - mean * mean;
  const float rstd = rsqrtf(var + 1e-5f);
  const float4 g4 = ((const float4*)g1)[t];
  const float4 b4 = ((const float4*)be1)[t];
  bf16x4 ov;
  ov[0] = (bf16)((v.x - mean) * rstd * g4.x + b4.x);
  ov[1] = (bf16)((v.y - mean) * rstd * g4.y + b4.y);
  ov[2] = (bf16)((v.z - mean) * rstd * g4.z + b4.z);
  ov[3] = (bf16)((v.w - mean) * rstd * g4.w + b4.w);
  ((bf16x4*)(qin_bf + (size_t)row * DM))[t] = ov;
}

// ---------------- LayerNorm (f32 in, bf16 out), one block per row of D=1024 ----------------
__global__ __launch_bounds__(256) void ln_kernel(const float* __restrict__ x,
                                                 const float* __restrict__ gam,
                                                 const float* __restrict__ bet,
                                                 bf16* __restrict__ out) {
  const int row = blockIdx.x, t = threadIdx.x;
  const float4 v = ((const float4*)(x + (size_t)row * DM))[t];
  float s  = v.x + v.y + v.z + v.w;
  float s2 = v.x * v.x + v.y * v.y + v.z * v.z + v.w * v.w;
#pragma unroll
  for (int m = 1; m < 64; m <<= 1) { s += __shfl_xor(s, m); s2 += __shfl_xor(s2, m); }
  __shared__ float red[8];
  const int w = t >> 6;
  if ((t & 63) == 0) { red[w] = s; red[4 + w] = s2; }
  __syncthreads();
  s  = red[0] + red[1] + red[2] + red[3];
  s2 = red[4] + red[5] + red[6] + red[7];
  const float mean = s * (1.f / DM);
  const float var  = s2 * (1.f / DM) - mean * mean;
  const float rstd = rsqrtf(var + 1e-5f);
  const float4 g4 = ((const float4*)gam)[t];
  const float4 b4 = ((const float4*)bet)[t];
  bf16x4 ov;
  ov[0] = (bf16)((v.x - mean) * rstd * g4.x + b4.x);
  ov[1] = (bf16)((v.y - mean) * rstd * g4.y + b4.y);
  ov[2] = (bf16)((v.z - mean) * rstd * g4.z + b4.z);
  ov[3] = (bf16)((v.w - mean) * rstd * g4.w + b4.w);
  ((bf16x4*)(out + (size_t)row * DM))[t] = ov;
}

// ---------------- bf16 MFMA GEMM v2: prefetch double-buffer + swizzled LDS ----------------
enum { EPI_QKV = 0, EPI_O = 3, EPI_F1 = 4, EPI_F2 = 5 };

struct GParams {
  const bf16* A;    // A operand (M x K, K-contig)
  const bf16* A2;   // QKV: A for n0 >= 1024 (enc)
  const bf16* W;    // weights (N x K, K-contig)
  const float* b0;  // bias (QKV: bq)
  const float* b1;  // QKV: bk
  const float* b2;  // QKV: bv
  const float* resid;
  void* out;        // QKV: Q
  void* out1;       // QKV: K
  void* out2;       // QKV: V^T
  int N;
  int K;
};

template <int MODE, int BN, int BK>
__global__ __launch_bounds__(256, 3) void gemm2(GParams p) {
  constexpr int BM = 128;
  constexpr int WTM = (BN == 128) ? 64 : 32;  // wave tile rows
  constexpr int MI = WTM / 16;
  __shared__ __align__(16) bf16 As[2][BM * BK];
  __shared__ __align__(16) bf16 Bs[2][BN * BK];
  const int t = threadIdx.x, lane = t & 63, w = t >> 6;
  const int lr = lane & 15, lg = lane >> 4;
  const int wr = (BN == 128) ? (w >> 1) : w;
  const int wc = (BN == 128) ? (w & 1) : 0;
  const int m0 = blockIdx.x * BM, n0 = blockIdx.y * BN;
  const bf16* Ap = (MODE == EPI_QKV && n0 >= 1024) ? p.A2 : p.A;
  const f32x4 FZ = {0.f, 0.f, 0.f, 0.f};
  f32x4 acc[MI][4];
#pragma unroll
  for (int i = 0; i < MI; ++i)
#pragma unroll
    for (int j = 0; j < 4; ++j) acc[i][j] = FZ;

  const int nk = p.K / BK;
  // prologue: stage tile 0
  stage_tile<BM, BK>(&Ap[(size_t)m0 * p.K], p.K, As[0], t);
  stage_tile<BN, BK>(&p.W[(size_t)n0 * p.K], p.K, Bs[0], t);
  asm volatile("s_waitcnt vmcnt(0)" ::: "memory");
  __syncthreads();

  int cur = 0;
  for (int kt = 0; kt < nk; ++kt) {
    // prefetch next tile into the other buffer (loads fly during compute)
    if (kt + 1 < nk) {
      stage_tile<BM, BK>(&Ap[(size_t)m0 * p.K + (size_t)(kt + 1) * BK], p.K, As[cur ^ 1], t);
      stage_tile<BN, BK>(&p.W[(size_t)n0 * p.K + (size_t)(kt + 1) * BK], p.K, Bs[cur ^ 1], t);
    }
    const bf16* Asl = As[cur];
    const bf16* Bsl = Bs[cur];
#pragma unroll
    for (int kh = 0; kh < BK / 32; ++kh) {
      bf16x8 af[MI], bfr[4];
#pragma unroll
      for (int i = 0; i < MI; ++i) {
        const int row = wr * WTM + i * 16 + lr;
        const int c = (kh * 4 + lg) ^ swz<BK>(row);
        af[i] = *(const bf16x8*)&Asl[row * BK + c * 8];
      }
#pragma unroll
      for (int j = 0; j < 4; ++j) {
        const int row = wc * 64 + j * 16 + lr;
        const int c = (kh * 4 + lg) ^ swz<BK>(row);
        bfr[j] = *(const bf16x8*)&Bsl[row * BK + c * 8];
      }
#pragma unroll
      for (int i = 0; i < MI; ++i)
#pragma unroll
        for (int j = 0; j < 4; ++j) acc[i][j] = MFMA16(af[i], bfr[j], acc[i][j]);
    }
    asm volatile("s_waitcnt vmcnt(0)" ::: "memory");
    __syncthreads();
    cur ^= 1;
  }

  // epilogue: C/D frag mapping row = 4*lg + g, col = lr (m89/m91-verified)
#pragma unroll
  for (int i = 0; i < MI; ++i) {
#pragma unroll
    for (int j = 0; j < 4; ++j) {
      const int c = n0 + wc * 64 + j * 16 + lr;
      float bj;
      if constexpr (MODE == EPI_QKV)
        bj = (c < 1024 ? p.b0 : c < 2048 ? p.b1 : p.b2)[c & 1023];
      else
        bj = p.b0[c];
#pragma unroll
      for (int g = 0; g < 4; ++g) {
        const int r = m0 + wr * WTM + i * 16 + 4 * lg + g;  // token = l*NB + b
        float v = acc[i][j][g] + bj;
        if constexpr (MODE == EPI_QKV) {
          const int cl = c & 1023;
          const size_t sidx = (((size_t)((r & 3) * NH + (cl >> 6)) << 10) + (r >> 2)) * DKH + (cl & 63);
          if (c < 1024)
            ((bf16*)p.out)[sidx] = (bf16)(v * 0.125f);  // 1/sqrt(dk) folded into Q
          else if (c < 2048)
            ((bf16*)p.out1)[sidx] = (bf16)v;
          else  // V stored TRANSPOSED per head: (bh, d, kv)
            ((bf16*)p.out2)[(((size_t)((r & 3) * NH + (cl >> 6)) * DKH + (cl & 63)) << 10) + (r >> 2)] = (bf16)v;
        } else if constexpr (MODE == EPI_O) {
          const size_t idx = (size_t)r * p.N + c;
          ((float*)p.out)[idx] = v + p.resid[idx];
        } else if constexpr (MODE == EPI_F1) {
          ((bf16*)p.out)[(size_t)r * p.N + c] = (bf16)fmaxf(v, 0.f);
        } else {  // EPI_F2
          const size_t idx = (size_t)r * p.N + c;
          ((float*)p.out)[idx] = v + p.resid[idx];
        }
      }
    }
  }
}

// ---------------- flash attention v3 ----------------
// 8 waves x 16 q rows; KV tile 64 double-buffered; XCD-swizzled grid;
// conflict-free swizzled K/V LDS reads; defer-max online softmax (THR=8).
__global__ __launch_bounds__(512, 4) void attn_kernel(const bf16* __restrict__ Qg,
                                                      const bf16* __restrict__ Kg,
                                                      const bf16* __restrict__ Vtg,
                                                      const unsigned char* __restrict__ smask,
                                                      bf16* __restrict__ Og) {
  __shared__ __align__(16) bf16 Ks[2][4096];   // [buf][kc(2)][kv(64)][32] d-chunked, chunk-swizzled
  __shared__ __align__(16) bf16 Vs[2][4096];   // [buf][kvc(2)][d(64)][32] kv-chunked, chunk-swizzled
  __shared__ __align__(16) bf16 Ps[8][1152];   // per-wave P, [16][72] padded
  const int t = threadIdx.x, lane = t & 63, w = t >> 6;
  const int lr = lane & 15, lg = lane >> 4;
  // work mapping: id = a*64 + qt*8 + r, bh = a*8 + r  (id%8 == bh%8 -> XCD share)
  const int id = blockIdx.x;
  const int bh = ((id >> 6) << 3) | (id & 7);
  const int qt = (id >> 3) & 7;
  const int b = bh >> 4, h = bh & 15;
  const int q0 = qt * 128 + w * 16;
  const size_t base = (size_t)bh << 16;  // bh * SEQ * DKH

  bf16x8 qa[2];
#pragma unroll
  for (int c = 0; c < 2; ++c)
    qa[c] = *(const bf16x8*)&Qg[base + (size_t)(q0 + lr) * DKH + c * 32 + lg * 8];

  const f32x4 FZ = {0.f, 0.f, 0.f, 0.f};
  f32x4 o[4];
  float mrun[4], lrun[4];
#pragma unroll
  for (int g = 0; g < 4; ++g) { mrun[g] = -INFINITY; lrun[g] = 0.f; o[g] = FZ; }

  // staging geometry: off = t*8; hi = kv/d-half, mid = row, chunk swizzled by (row>>1)&3
  const int soff = t * 8;
  const int shi = soff >> 11, smid = (soff >> 5) & 63;
  const int ssc = (((soff >> 3) & 3) ^ ((smid >> 1) & 3)) << 3;

  // prologue: stage tile 0
  gload_lds16(&Kg[base + (size_t)smid * DKH + shi * 32 + ssc], &Ks[0][soff]);
  gload_lds16(&Vtg[base + (size_t)smid * SEQ + shi * 32 + ssc], &Vs[0][soff]);
  asm volatile("s_waitcnt vmcnt(0)" ::: "memory");
  __syncthreads();

  // fragment-read chunk swizzle: row = n*16+lr -> sigma = (lr>>1)&3
  const int rsw = ((lr >> 1) & 3);

  int cur = 0;
  for (int kt = 0; kt < SEQ / 64; ++kt) {
    const int kv0 = kt * 64;
    // prefetch next KV tile into other buffer (flies under compute)
    if (kt + 1 < SEQ / 64) {
      gload_lds16(&Kg[base + (size_t)(kv0 + 64 + smid) * DKH + shi * 32 + ssc], &Ks[cur ^ 1][soff]);
      gload_lds16(&Vtg[base + (size_t)smid * SEQ + kv0 + 64 + shi * 32 + ssc], &Vs[cur ^ 1][soff]);
    }

    // QK^T
    f32x4 s[4];
#pragma unroll
    for (int n = 0; n < 4; ++n) s[n] = FZ;
#pragma unroll
    for (int c = 0; c < 2; ++c) {
      bf16x8 kb[4];
#pragma unroll
      for (int n = 0; n < 4; ++n)
        kb[n] = *(const bf16x8*)&Ks[cur][c * 2048 + (n * 16 + lr) * 32 + ((lg ^ rsw) << 3)];
      __builtin_amdgcn_s_setprio(1);
#pragma unroll
      for (int n = 0; n < 4; ++n) s[n] = MFMA16(qa[c], kb[n], s[n]);
      __builtin_amdgcn_s_setprio(0);
    }

    // mask add
    float madd[4];
#pragma unroll
    for (int n = 0; n < 4; ++n)
      madd[n] = smask[(size_t)(kv0 + n * 16 + lr) * NB + b] ? -1e10f : 0.f;
#pragma unroll
    for (int n = 0; n < 4; ++n)
#pragma unroll
      for (int g = 0; g < 4; ++g) s[n][g] += madd[n];

    // online softmax with defer-max (row = q0 + 4*lg + g; 16 lanes differ in lane bits 0-3)
    float tm4[4];
    bool needany = false;
#pragma unroll
    for (int g = 0; g < 4; ++g) {
      float tm = fmaxf(fmaxf(s[0][g], s[1][g]), fmaxf(s[2][g], s[3][g]));
      tm = fmaxf(tm, __shfl_xor(tm, 1));
      tm = fmaxf(tm, __shfl_xor(tm, 2));
      tm = fmaxf(tm, __shfl_xor(tm, 4));
      tm = fmaxf(tm, __shfl_xor(tm, 8));
      tm4[g] = tm;
      needany |= (tm > mrun[g] + 8.f);
    }
    if (__any(needany)) {
#pragma unroll
      for (int g = 0; g < 4; ++g) {
        const float mnew = fmaxf(mrun[g], tm4[g]);
        const float sc = __expf(mrun[g] - mnew);
        mrun[g] = mnew;
        lrun[g] *= sc;
#pragma unroll
        for (int n = 0; n < 4; ++n) o[n][g] *= sc;
      }
    }
#pragma unroll
    for (int g = 0; g < 4; ++g) {
      float ts = 0.f;
#pragma unroll
      for (int n = 0; n < 4; ++n) {
        const float p = __expf(s[n][g] - mrun[g]);
        s[n][g] = p;
        ts += p;
      }
      ts += __shfl_xor(ts, 1);
      ts += __shfl_xor(ts, 2);
      ts += __shfl_xor(ts, 4);
      ts += __shfl_xor(ts, 8);
      lrun[g] += ts;
    }

    // P: D-fragment layout -> LDS -> A-fragment layout (bf16), padded stride 72
    bf16* Pw = &Ps[w][0];
#pragma unroll
    for (int n = 0; n < 4; ++n)
#pragma unroll
      for (int g = 0; g < 4; ++g)
        Pw[(4 * lg + g) * 72 + n * 16 + lr] = (bf16)s[n][g];
    __builtin_amdgcn_sched_barrier(0);  // keep ds_reads after ds_writes

    // PV
#pragma unroll
    for (int c = 0; c < 2; ++c) {
      const bf16x8 pa = *(const bf16x8*)&Pw[lr * 72 + c * 32 + lg * 8];
      bf16x8 vb[4];
#pragma unroll
      for (int n = 0; n < 4; ++n)
        vb[n] = *(const bf16x8*)&Vs[cur][c * 2048 + (n * 16 + lr) * 32 + ((lg ^ rsw) << 3)];
      __builtin_amdgcn_s_setprio(1);
#pragma unroll
      for (int n = 0; n < 4; ++n) o[n] = MFMA16(pa, vb[n], o[n]);
      __builtin_amdgcn_s_setprio(0);
    }

    asm volatile("s_waitcnt vmcnt(0)" ::: "memory");
    __syncthreads();
    cur ^= 1;
  }

  // write attn output, token-major (l*NB+b, h*64+d), bf16
#pragma unroll
  for (int g = 0; g < 4; ++g) {
    const int l = q0 + 4 * lg + g;
    const float inv = 1.0f / lrun[g];
#pragma unroll
    for (int n = 0; n < 4; ++n)
      Og[(size_t)(l * NB + b) * DM + h * 64 + n * 16 + lr] = (bf16)(o[n][g] * inv);
  }
}

// ---------------- host orchestration ----------------
extern "C" void kernel_launch(void* const* d_in, const int* in_sizes, int n_in,
                              void* d_out, int out_size, void* d_ws, size_t ws_size,
                              hipStream_t stream) {
  const float* enc = (const float*)d_in[0];
  const float* emb = (const float*)d_in[1];
  const unsigned char* smask = (const unsigned char*)d_in[2];
  // d_in[3] tgt_mask, d_in[4..11] mmha_*, d_in[24..25] ln0_* are dead (sublayer 0 discarded)
  const float* wq = (const float*)d_in[12]; const float* bq = (const float*)d_in[13];
  const float* wk = (const float*)d_in[14]; const float* bk = (const float*)d_in[15];
  const float* wv = (const float*)d_in[16]; const float* bv = (const float*)d_in[17];
  const float* wo = (const float*)d_in[18]; const float* bo = (const float*)d_in[19];
  const float* w1 = (const float*)d_in[20]; const float* b1 = (const float*)d_in[21];
  const float* w2 = (const float*)d_in[22]; const float* b2 = (const float*)d_in[23];
  const float* g1 = (const float*)d_in[26]; const float* be1 = (const float*)d_in[27];
  const float* g2 = (const float*)d_in[28]; const float* be2 = (const float*)d_in[29];

  char* ws = (char*)d_ws;
  const size_t MB = (size_t)1 << 20;
  bf16* wqkv_bf = (bf16*)(ws + 0 * MB);   // 3072x1024 packed (Q|K|V)
  bf16* wo_bf   = (bf16*)(ws + 6 * MB);
  bf16* w1_bf   = (bf16*)(ws + 8 * MB);
  bf16* w2_bf   = (bf16*)(ws + 16 * MB);
  bf16* enc_bf  = (bf16*)(ws + 24 * MB);
  bf16* z_bf    = enc_bf;                 // alias: enc_bf dead after QKV proj
  bf16* qin_bf  = (bf16*)(ws + 32 * MB);
  bf16* attn_bf = qin_bf;                 // alias: qin dead after QKV proj
  bf16* Q_bf    = (bf16*)(ws + 40 * MB);
  bf16* K_bf    = (bf16*)(ws + 48 * MB);
  bf16* Vt_bf   = (bf16*)(ws + 56 * MB);
  float* encdec = (float*)(ws + 64 * MB);
  bf16* h_bf    = (bf16*)(ws + 80 * MB);

  // fused casts + LN1 (one dispatch)
  prep_kernel<<<20480, 256, 0, stream>>>(wq, wk, wv, wo, w1, w2, enc, emb, g1, be1,
                                         wqkv_bf, wo_bf, w1_bf, w2_bf, enc_bf, qin_bf);

  // fused Q|K|V projection: N=3072, grid (32,24)=768 blocks (3/CU)
  {
    GParams p{qin_bf, enc_bf, wqkv_bf, bq, bk, bv, nullptr, Q_bf, K_bf, Vt_bf, 3072, DM};
    gemm2<EPI_QKV, 128, 32><<<dim3(32, 24), 256, 0, stream>>>(p);
  }

  // flash attention: 512 blocks x 512 threads (XCD-swizzled 1-D grid)
  attn_kernel<<<512, 512, 0, stream>>>(Q_bf, K_bf, Vt_bf, smask, attn_bf);

  // O projection + residual(embedded) -> enc_dec (f32)
  {
    GParams p{attn_bf, nullptr, wo_bf, bo, nullptr, nullptr, emb, encdec, nullptr, nullptr, DM, DM};
    gemm2<EPI_O, 64, 64><<<dim3(32, 16), 256, 0, stream>>>(p);
  }

  // LN2(enc_dec) -> z
  ln_kernel<<<4096, 256, 0, stream>>>(encdec, g2, be2, z_bf);

  // FFN
  {
    GParams p{z_bf, nullptr, w1_bf, b1, nullptr, nullptr, nullptr, h_bf, nullptr, nullptr, DF, DM};
    gemm2<EPI_F1, 128, 32><<<dim3(32, 32), 256, 0, stream>>>(p);
  }
  {
    GParams p{h_bf, nullptr, w2_bf, b2, nullptr, nullptr, encdec, d_out, nullptr, nullptr, DM, DF};
    gemm2<EPI_F2, 64, 64><<<dim3(32, 16), 256, 0, stream>>>(p);
  }
}